// Round 15
// baseline (369.819 us; speedup 1.0000x reference)
//
#include <hip/hip_runtime.h>
#include <math.h>

// Problem constants (B=2, S=2048, H=1024, NH=8, HD=128)
static constexpr int Bz = 2;
static constexpr int Sq = 2048;
static constexpr int Hh = 1024;
static constexpr int NH = 8;
static constexpr int HD = 128;
static constexpr int H3 = 3072;
static constexpr int H6 = 6144;

typedef unsigned short ushort_t;
typedef float f32x4v __attribute__((ext_vector_type(4)));
typedef short s16x8 __attribute__((ext_vector_type(8)));

// Workspace layout in float units (×4 bytes). Peak 146.8 MB (< 152.04 known-good).
static constexpr size_t FUSED_OFF = 0;          // bf16 [4096][6144] = 12,582,912 f
static constexpr size_t A2_OFF    = 12582912;   // bf16 [4096][3072] =  6,291,456 f
static constexpr size_t HB_OFF    = 18874368;   // bf16 [4096][1024] (dead after gemm_silu)
static constexpr size_t WQT_OFF   = 20971520;   // bf16 [6144][1024] (dead after gemm_silu)
static constexpr size_t WOT_OFF   = 24117248;   // bf16 [1024][3072] =  1,572,864 f
static constexpr size_t QR_OFF    = 25690112;   // bf16 [4096][1024] =  2,097,152 f
static constexpr size_t KR_OFF    = 27787264;   // bf16 [4096][1024] =  2,097,152 f
static constexpr size_t VT_OFF    = 29884416;   // bf16 [16][128][2048] = 2,097,152 f
static constexpr size_t TAB_OFF   = 31981568;   // f32 S*64 float2 = 262,144 f
static constexpr size_t FLAG_OFF  = 32243712;   // 1 int (+pad)
static constexpr size_t TSB_OFF   = 32243716;   // bf16 [2][2048][2048] = 4,194,304 f
static constexpr size_t MBITS_OFF = 36438020;   // u32 [2][2048][64] = 262,144 f -> ends 36,700,164 f

__device__ __forceinline__ float silu_(float x) { return x / (1.0f + expf(-x)); }
__device__ __forceinline__ ushort_t f2bf(float x) {
  unsigned int u = __float_as_uint(x);
  u += 0x7fffu + ((u >> 16) & 1u);
  return (ushort_t)(u >> 16);
}
__device__ __forceinline__ float bf2f(ushort_t u) {
  return __uint_as_float(((unsigned int)u) << 16);
}
// async global->LDS 16B: per-lane global src, wave-uniform LDS base (+lane*16B by HW)
__device__ __forceinline__ void g2l16(const ushort_t* g, ushort_t* l) {
  __builtin_amdgcn_global_load_lds(
      (const __attribute__((address_space(1))) unsigned int*)g,
      (__attribute__((address_space(3))) unsigned int*)l, 16, 0, 0);
}

// ---------------- fused conversions + rope table + mask detect:
// blocks 0..4095: hidden f32->bf16 | 4096..10239: Wqkvu transpose | 10240..13311: Wout
// transpose | 13312..13823: rope table | 13824: mask dtype detect
__global__ __launch_bounds__(256) void hstu_cvt_all(const float* __restrict__ hidden,
                                                    ushort_t* __restrict__ hb,
                                                    const float* __restrict__ Wq,
                                                    ushort_t* __restrict__ wqt,
                                                    const float* __restrict__ Wo,
                                                    ushort_t* __restrict__ wot,
                                                    float* __restrict__ tab,
                                                    const unsigned int* __restrict__ m,
                                                    int* __restrict__ flag) {
  __shared__ float tbuf[32][33];
  const int blk = blockIdx.x;
  if (blk >= 13824) {  // detect: any 32-bit word > 1 => byte-packed bools
    __shared__ int s_any;
    if (threadIdx.x == 0) s_any = 0;
    __syncthreads();
    int any = 0;
    for (int i = threadIdx.x; i < 8192; i += 256)
      if (m[i] > 1u) any = 1;
    if (any) s_any = 1;
    __syncthreads();
    if (threadIdx.x == 0) *flag = s_any;
    return;
  }
  if (blk >= 13312) {  // rope table
    int t = (blk - 13312) * 256 + threadIdx.x;  // < S*64
    int i = t & 63;
    int s = t >> 6;
    float inv = powf(10000.0f, -(float)i / 64.0f);
    float sn, cs;
    sincosf((float)s * inv, &sn, &cs);
    tab[2 * t + 0] = cs;
    tab[2 * t + 1] = sn;
    return;
  }
  if (blk < 4096) {  // hidden copy-convert
    const int idx = blk * 256 + threadIdx.x;
    float4 v = *(const float4*)&hidden[(size_t)idx * 4];
    ushort4 o;
    o.x = f2bf(v.x); o.y = f2bf(v.y); o.z = f2bf(v.z); o.w = f2bf(v.w);
    *(ushort4*)&hb[(size_t)idx * 4] = o;
    return;
  }
  const float* in;
  ushort_t* out;
  int K, N, n0, k0;
  if (blk < 4096 + 6144) {
    const int j = blk - 4096;
    in = Wq; out = wqt; K = 1024; N = 6144;
    n0 = (j % 192) * 32; k0 = (j / 192) * 32;
  } else {
    const int j = blk - 10240;
    in = Wo; out = wot; K = 3072; N = 1024;
    n0 = (j % 32) * 32; k0 = (j / 32) * 32;
  }
  const int c = threadIdx.x & 31, rr = threadIdx.x >> 5;
#pragma unroll
  for (int p = 0; p < 4; ++p)
    tbuf[rr + p * 8][c] = in[(size_t)(k0 + rr + p * 8) * N + n0 + c];
  __syncthreads();
#pragma unroll
  for (int p = 0; p < 4; ++p)
    out[(size_t)(n0 + rr + p * 8) * K + k0 + c] = f2bf(tbuf[c][rr + p * 8]);
}

// ---------------- MEGA: GEMM1 (blocks 0..1535) || msk (blocks 1536..5631).
__global__ __launch_bounds__(256) void hstu_gemm_silu_msk(
    const ushort_t* __restrict__ A, const ushort_t* __restrict__ Bt,
    ushort_t* __restrict__ C, const int* __restrict__ mask32,
    const unsigned char* __restrict__ mask8, const int* __restrict__ mflag,
    const float* __restrict__ bias, ushort_t* __restrict__ tsb,
    unsigned char* __restrict__ mbits) {
  __shared__ ushort_t As[128 * 64];
  __shared__ ushort_t Bs[128 * 64];
  const int blk = blockIdx.x;
  const int tid = threadIdx.x;
  if (blk >= 1536) {  // ---- msk branch (no barriers, no LDS use)
    const size_t gt = (size_t)(blk - 1536) * 256 + tid;  // over B*S*S/8
    const size_t base = gt * 8;
    const int m_u8 = *mflag;
    int mk[8];
    if (m_u8) {
      uchar4 a = *(const uchar4*)&mask8[base];
      uchar4 b = *(const uchar4*)&mask8[base + 4];
      mk[0] = a.x; mk[1] = a.y; mk[2] = a.z; mk[3] = a.w;
      mk[4] = b.x; mk[5] = b.y; mk[6] = b.z; mk[7] = b.w;
    } else {
      int4 a = *(const int4*)&mask32[base];
      int4 b = *(const int4*)&mask32[base + 4];
      mk[0] = a.x; mk[1] = a.y; mk[2] = a.z; mk[3] = a.w;
      mk[4] = b.x; mk[5] = b.y; mk[6] = b.z; mk[7] = b.w;
    }
    float4 b0 = *(const float4*)&bias[base];
    float4 b1 = *(const float4*)&bias[base + 4];
    float bb[8] = {b0.x, b0.y, b0.z, b0.w, b1.x, b1.y, b1.z, b1.w};
    ushort_t ts[8];
    unsigned int byte = 0;
#pragma unroll
    for (int i = 0; i < 8; ++i) {
      ts[i] = f2bf(mk[i] ? bb[i] : 0.0f);
      byte |= (mk[i] ? 1u : 0u) << i;
    }
    *(s16x8*)&tsb[base] = *(s16x8*)ts;
    mbits[gt] = (unsigned char)byte;
    return;
  }
  // ---- GEMM branch: fused = silu(hidden_bf @ WqT^T)  M=4096 N=6144 K=1024
  constexpr int K = 1024, N = H6;
  const int lane = tid & 63, wid = tid >> 6;
  const int lo4 = lane & 15, hi2 = lane >> 4;
  const int wr = wid >> 1, wc = wid & 1;
  const int row0 = (blk / 48) * 128, col0 = (blk % 48) * 128;
  const int srow = lane >> 3, scol = (lane & 7) * 8;
  f32x4v acc[4][4];
#pragma unroll
  for (int i = 0; i < 4; ++i)
#pragma unroll
    for (int j = 0; j < 4; ++j) acc[i][j] = {0.f, 0.f, 0.f, 0.f};

  for (int k0 = 0; k0 < K; k0 += 64) {
    __syncthreads();
#pragma unroll
    for (int i = 0; i < 4; ++i) {
      const int rb = wid * 32 + i * 8;
      g2l16(&A[(size_t)(row0 + rb + srow) * K + k0 + scol], &As[rb * 64]);
      g2l16(&Bt[(size_t)(col0 + rb + srow) * K + k0 + scol], &Bs[rb * 64]);
    }
    __syncthreads();
#pragma unroll
    for (int kc = 0; kc < 2; ++kc) {
      s16x8 af[4], bfr[4];
#pragma unroll
      for (int mi = 0; mi < 4; ++mi)
        af[mi] = *(const s16x8*)&As[(wr * 64 + mi * 16 + lo4) * 64 + kc * 32 + hi2 * 8];
#pragma unroll
      for (int nj = 0; nj < 4; ++nj)
        bfr[nj] = *(const s16x8*)&Bs[(wc * 64 + nj * 16 + lo4) * 64 + kc * 32 + hi2 * 8];
#pragma unroll
      for (int mi = 0; mi < 4; ++mi)
#pragma unroll
        for (int nj = 0; nj < 4; ++nj)
          acc[mi][nj] = __builtin_amdgcn_mfma_f32_16x16x32_bf16(af[mi], bfr[nj], acc[mi][nj], 0, 0, 0);
    }
  }
#pragma unroll
  for (int mi = 0; mi < 4; ++mi)
#pragma unroll
    for (int nj = 0; nj < 4; ++nj)
#pragma unroll
      for (int r = 0; r < 4; ++r) {
        const int row = row0 + wr * 64 + mi * 16 + hi2 * 4 + r;
        const int col = col0 + wc * 64 + nj * 16 + lo4;
        C[(size_t)row * N + col] = f2bf(silu_(acc[mi][nj][r]));
      }
}

// ---------------- fused: rope precompute (2048 blk) + V transpose (4096 blk)
__global__ __launch_bounds__(256) void hstu_prep2(const ushort_t* __restrict__ fused,
                                                  const float2* __restrict__ tab,
                                                  ushort_t* __restrict__ qr,
                                                  ushort_t* __restrict__ kr,
                                                  ushort_t* __restrict__ vt) {
  __shared__ ushort_t tbuf[32][36];
  const int blk = blockIdx.x;
  if (blk < 2048) {  // rope
    const int idx = blk * 256 + threadIdx.x;
    const int row = idx >> 7;
    const int cg = (idx & 127) * 8;
    const int s = row & (Sq - 1);
    const float2* trow = &tab[(size_t)s * 64 + ((cg & 127) >> 1)];
    float2 t[4];
#pragma unroll
    for (int p = 0; p < 4; ++p) t[p] = trow[p];
    s16x8 q8 = *(const s16x8*)&fused[(size_t)row * H6 + 4 * Hh + cg];
    s16x8 k8 = *(const s16x8*)&fused[(size_t)row * H6 + 5 * Hh + cg];
    ushort_t qo[8], ko[8];
#pragma unroll
    for (int p = 0; p < 4; ++p) {
      float qx = bf2f((ushort_t)q8[2 * p]), qy = bf2f((ushort_t)q8[2 * p + 1]);
      float kx = bf2f((ushort_t)k8[2 * p]), ky = bf2f((ushort_t)k8[2 * p + 1]);
      qo[2 * p] = f2bf(qx * t[p].x - qy * t[p].y);
      qo[2 * p + 1] = f2bf(qy * t[p].x + qx * t[p].y);
      ko[2 * p] = f2bf(kx * t[p].x - ky * t[p].y);
      ko[2 * p + 1] = f2bf(ky * t[p].x + kx * t[p].y);
    }
    *(s16x8*)&qr[(size_t)row * Hh + cg] = *(s16x8*)qo;
    *(s16x8*)&kr[(size_t)row * Hh + cg] = *(s16x8*)ko;
    return;
  }
  // vt: vt[(b*8+h)*128+dd][m] = V[b][m][h*128+dd]
  const int j = blk - 2048;
  const int m0 = (j & 63) * 32, d0 = ((j >> 6) & 3) * 32, bh = j >> 8;
  const int b = bh >> 3, h = bh & 7;
  const int r = threadIdx.x >> 3, cg = (threadIdx.x & 7) * 4;
  *(ushort4*)&tbuf[r][cg] =
      *(const ushort4*)&fused[(size_t)(b * Sq + m0 + r) * H6 + 3 * Hh + h * HD + d0 + cg];
  __syncthreads();
  ushort4 o;
  o.x = tbuf[cg + 0][r]; o.y = tbuf[cg + 1][r]; o.z = tbuf[cg + 2][r]; o.w = tbuf[cg + 3][r];
  *(ushort4*)&vt[(size_t)(bh * HD + d0 + r) * Sq + m0 + cg] = o;
}

// ---------------- GEMM2: out = A2 @ WoT^T + b_out + hidden  M=4096 N=1024 K=3072, f32 out
__global__ __launch_bounds__(256) void hstu_gemm_out(const ushort_t* __restrict__ A,
                                                     const ushort_t* __restrict__ Bt,
                                                     const float* __restrict__ bout,
                                                     const float* __restrict__ hidden,
                                                     float* __restrict__ C) {
  constexpr int K = H3, N = Hh;
  __shared__ ushort_t As[128 * 64];
  __shared__ ushort_t Bs[64 * 64];
  const int tid = threadIdx.x, lane = tid & 63, wid = tid >> 6;
  const int lo4 = lane & 15, hi2 = lane >> 4;
  const int wr = wid >> 1, wc = wid & 1;
  const int row0 = blockIdx.y * 128, col0 = blockIdx.x * 64;
  const int srow = lane >> 3, scol = (lane & 7) * 8;
  f32x4v acc[4][2];
#pragma unroll
  for (int i = 0; i < 4; ++i)
#pragma unroll
    for (int j = 0; j < 2; ++j) acc[i][j] = {0.f, 0.f, 0.f, 0.f};

  for (int k0 = 0; k0 < K; k0 += 64) {
    __syncthreads();
#pragma unroll
    for (int i = 0; i < 4; ++i) {
      const int rb = wid * 32 + i * 8;
      g2l16(&A[(size_t)(row0 + rb + srow) * K + k0 + scol], &As[rb * 64]);
    }
#pragma unroll
    for (int i = 0; i < 2; ++i) {
      const int rb = wid * 16 + i * 8;
      g2l16(&Bt[(size_t)(col0 + rb + srow) * K + k0 + scol], &Bs[rb * 64]);
    }
    __syncthreads();
#pragma unroll
    for (int kc = 0; kc < 2; ++kc) {
      s16x8 af[4], bfr[2];
#pragma unroll
      for (int mi = 0; mi < 4; ++mi)
        af[mi] = *(const s16x8*)&As[(wr * 64 + mi * 16 + lo4) * 64 + kc * 32 + hi2 * 8];
#pragma unroll
      for (int nj = 0; nj < 2; ++nj)
        bfr[nj] = *(const s16x8*)&Bs[(wc * 32 + nj * 16 + lo4) * 64 + kc * 32 + hi2 * 8];
#pragma unroll
      for (int mi = 0; mi < 4; ++mi)
#pragma unroll
        for (int nj = 0; nj < 2; ++nj)
          acc[mi][nj] = __builtin_amdgcn_mfma_f32_16x16x32_bf16(af[mi], bfr[nj], acc[mi][nj], 0, 0, 0);
    }
  }
#pragma unroll
  for (int mi = 0; mi < 4; ++mi)
#pragma unroll
    for (int nj = 0; nj < 2; ++nj)
#pragma unroll
      for (int r = 0; r < 4; ++r) {
        const int row = row0 + wr * 64 + mi * 16 + hi2 * 4 + r;
        const int col = col0 + wc * 32 + nj * 16 + lo4;
        C[(size_t)row * N + col] = acc[mi][nj][r] + bout[col] + hidden[(size_t)row * N + col];
      }
}

// ---------------- fused attention (R13 structure; ts PV A-frags now direct-from-global,
// register double-buffered — Pl[2] plane and its LDS roundtrip deleted).
// Block: (h, nblock, b), 8 waves, KVBLK=32, 3 barriers/iter, T14 split staging.
__global__ __launch_bounds__(512, 4) void hstu_attn(const ushort_t* __restrict__ fused,
                                                    const ushort_t* __restrict__ qr,
                                                    const ushort_t* __restrict__ kr,
                                                    const ushort_t* __restrict__ vt,
                                                    const ushort_t* __restrict__ tsb,
                                                    const unsigned int* __restrict__ mbits32,
                                                    ushort_t* __restrict__ a2) {
  __shared__ __align__(16) ushort_t Ks[32][136];
  __shared__ __align__(16) ushort_t KRs[32][136];
  __shared__ __align__(16) ushort_t Vt[128][40];   // Vt[dd][m]
  __shared__ __align__(16) ushort_t Pl[2][64][40]; // 0=plain 1=rope
  __shared__ unsigned int Mt32[64];                // bit-packed mask row per n

  const int tid = threadIdx.x;
  const int lane = tid & 63;
  const int wid = tid >> 6;  // 0..7
  const int lo4 = lane & 15;
  const int hi2 = lane >> 4;
  const int h = blockIdx.x;        // x = head -> linear%8 = h -> XCD pinning
  const int n0 = blockIdx.y * 64;
  const int b = blockIdx.z;
  const float ivs = 1.0f / 2048.0f;
  constexpr int NT = Sq / 32;

  const int rh2 = wid >> 2;  // PV row-half
  const int cq = wid & 3;    // PV dd-quarter

  // staging index constants
  const int krow = tid >> 4, kcol = (tid & 15) * 8;       // K/KR: 32 x 128
  const int vdd = tid >> 2, vmg = (tid & 3) * 8;          // Vt: 128 x 32
  const size_t kbase = (size_t)b * Sq * H6 + 5 * Hh + h * HD + kcol;
  const size_t krbase = (size_t)b * Sq * Hh + h * HD + kcol;
  const size_t vbase = (size_t)((b * NH + h) * HD + vdd) * Sq + vmg;
  const size_t mbase = (size_t)(b * Sq + n0 + lane) * 64;  // u32 stride 64/row
  // ts PV A-frag base: rows rh2*32 + rt*16 + lo4, cols m0 + hi2*8
  const size_t tsbase = (size_t)(b * Sq + n0 + rh2 * 32 + lo4) * Sq + hi2 * 8;

  // ---- hoist Q fragments: wave = (type t_w, row-quarter rq)
  const int t_w = wid >> 2;  // 0=plain 1=rope
  const int rq = wid & 3;
  s16x8 qf[4];
  {
    const int row = tid >> 4;
    const int colg = (tid & 15) * 8;
#pragma unroll
    for (int half = 0; half < 2; ++half) {
      const size_t gr = (size_t)(b * Sq + n0 + half * 32 + row);
      *(s16x8*)&Ks[row][colg] = *(const s16x8*)&fused[gr * H6 + 4 * Hh + h * HD + colg];
      *(s16x8*)&KRs[row][colg] = *(const s16x8*)&qr[gr * Hh + h * HD + colg];
      __syncthreads();
      if ((rq >> 1) == half) {
        const int lrow = (rq & 1) * 16 + lo4;
        const ushort_t(*Qsrc)[136] = t_w ? KRs : Ks;
#pragma unroll
        for (int c = 0; c < 4; ++c)
          qf[c] = *(const s16x8*)&Qsrc[lrow][c * 32 + hi2 * 8];
      }
      __syncthreads();
    }
  }

  const f32x4v zero4 = {0.f, 0.f, 0.f, 0.f};
  f32x4v accO[3][2][2];
#pragma unroll
  for (int t = 0; t < 3; ++t)
#pragma unroll
    for (int rt = 0; rt < 2; ++rt)
#pragma unroll
      for (int ct = 0; ct < 2; ++ct) accO[t][rt][ct] = zero4;

  // prefetch registers
  s16x8 kreg, krreg, vreg, tsA_nxt, tsB_nxt;
  unsigned int mreg;
#define LOADT(T)                                                            \
  {                                                                         \
    const size_t moff = (size_t)(T) * 32;                                   \
    kreg = *(const s16x8*)&fused[kbase + (moff + krow) * H6];               \
    krreg = *(const s16x8*)&kr[krbase + (moff + krow) * Hh];                \
    vreg = *(const s16x8*)&vt[vbase + moff];                                \
    tsA_nxt = *(const s16x8*)&tsb[tsbase + moff];                           \
    tsB_nxt = *(const s16x8*)&tsb[tsbase + 16 * Sq + moff];                 \
    if (wid == 4) mreg = mbits32[mbase + (T)];                              \
  }
#define WRITET()                                                            \
  {                                                                         \
    *(s16x8*)&Ks[krow][kcol] = kreg;                                        \
    *(s16x8*)&KRs[krow][kcol] = krreg;                                      \
    *(s16x8*)&Vt[vdd][vmg] = vreg;                                          \
    if (wid == 4) Mt32[lane] = mreg;                                        \
  }

  LOADT(0);
  WRITET();
  __syncthreads();

  for (int t = 0; t < NT; ++t) {
    // tile t's ts frags (loaded one iteration ago; prologue for t=0)
    s16x8 tsA = tsA_nxt, tsB = tsB_nxt;
    if (t + 1 < NT) LOADT(t + 1);  // issue early (T14)
    // ---- scores: S^T via mfma(kf, qf); mask via bit-test on Mt32[n]
    {
      const ushort_t(*Kmat)[136] = t_w ? KRs : Ks;
      const int n = rq * 16 + lo4;
      const unsigned int bits = Mt32[n];
#pragma unroll
      for (int mt2 = 0; mt2 < 2; ++mt2) {
        f32x4v a = zero4;
#pragma unroll
        for (int c = 0; c < 4; ++c) {
          s16x8 kf = *(const s16x8*)&Kmat[mt2 * 16 + lo4][c * 32 + hi2 * 8];
          a = __builtin_amdgcn_mfma_f32_16x16x32_bf16(kf, qf[c], a, 0, 0, 0);
        }
        const int mb = mt2 * 16 + hi2 * 4;
        ushort4 po;
        po.x = ((bits >> (mb + 0)) & 1u) ? f2bf(fmaxf(a[0], 0.f) * ivs) : (ushort_t)0;
        po.y = ((bits >> (mb + 1)) & 1u) ? f2bf(fmaxf(a[1], 0.f) * ivs) : (ushort_t)0;
        po.z = ((bits >> (mb + 2)) & 1u) ? f2bf(fmaxf(a[2], 0.f) * ivs) : (ushort_t)0;
        po.w = ((bits >> (mb + 3)) & 1u) ? f2bf(fmaxf(a[3], 0.f) * ivs) : (ushort_t)0;
        *(ushort4*)&Pl[t_w][n][mb] = po;
      }
    }
    __syncthreads();
    // ---- PV: wave (rh2, cq): O[32 rows][32 dd] x 3 types (ts A-frags from registers)
    {
      s16x8 af[3][2];
#pragma unroll
      for (int rt = 0; rt < 2; ++rt) {
        af[0][rt] = *(const s16x8*)&Pl[0][rh2 * 32 + rt * 16 + lo4][hi2 * 8];
        af[1][rt] = *(const s16x8*)&Pl[1][rh2 * 32 + rt * 16 + lo4][hi2 * 8];
      }
      af[2][0] = tsA;
      af[2][1] = tsB;
      s16x8 bfv[2];
#pragma unroll
      for (int ct = 0; ct < 2; ++ct)
        bfv[ct] = *(const s16x8*)&Vt[cq * 32 + ct * 16 + lo4][hi2 * 8];
#pragma unroll
      for (int ty = 0; ty < 3; ++ty)
#pragma unroll
        for (int rt = 0; rt < 2; ++rt)
#pragma unroll
          for (int ct = 0; ct < 2; ++ct)
            accO[ty][rt][ct] =
                __builtin_amdgcn_mfma_f32_16x16x32_bf16(af[ty][rt], bfv[ct], accO[ty][rt][ct], 0, 0, 0);
    }
    __syncthreads();
    // ---- write prefetched tile t+1 into LDS (write late, T14)
    if (t + 1 < NT) WRITET();
    __syncthreads();
  }
#undef LOADT
#undef WRITET

  // ---- epilogue: a2 = acc * gated (gated = fused[:, :3H], same 3H coordinate)
  const int toff[3] = {256, 0, 128};
#pragma unroll
  for (int ty = 0; ty < 3; ++ty)
#pragma unroll
    for (int rt = 0; rt < 2; ++rt)
#pragma unroll
      for (int ct = 0; ct < 2; ++ct)
#pragma unroll
        for (int r = 0; r < 4; ++r) {
          const int n = n0 + rh2 * 32 + rt * 16 + hi2 * 4 + r;
          const int dd = cq * 32 + ct * 16 + lo4;
          const int col3 = h * 384 + toff[ty] + dd;
          const float g = bf2f(fused[(size_t)(b * Sq + n) * H6 + col3]);
          a2[(size_t)(b * Sq + n) * H3 + col3] = f2bf(accO[ty][rt][ct][r] * g);
        }
}

// ---------------- RMS norm in-place (4096 rows x 1024), f32
__global__ __launch_bounds__(256) void hstu_rms(float* __restrict__ y,
                                                const float* __restrict__ w) {
  __shared__ float red[4];
  const int row = blockIdx.x;
  const int tid = threadIdx.x;
  float4 v = *(float4*)&y[(size_t)row * Hh + tid * 4];
  float ss = v.x * v.x + v.y * v.y + v.z * v.z + v.w * v.w;
#pragma unroll
  for (int o = 32; o > 0; o >>= 1) ss += __shfl_down(ss, o);
  if ((tid & 63) == 0) red[tid >> 6] = ss;
  __syncthreads();
  const float tot = red[0] + red[1] + red[2] + red[3];
  const float r = 1.0f / sqrtf(tot / (float)Hh + 1e-6f);
  float4 wv = *(const float4*)&w[tid * 4];
  v.x *= r * wv.x;
  v.y *= r * wv.y;
  v.z *= r * wv.z;
  v.w *= r * wv.w;
  *(float4*)&y[(size_t)row * Hh + tid * 4] = v;
}

extern "C" void kernel_launch(void* const* d_in, const int* in_sizes, int n_in,
                              void* d_out, int out_size, void* d_ws, size_t ws_size,
                              hipStream_t stream) {
  const float* hidden = (const float*)d_in[0];
  const void* mask = d_in[1];
  const float* bias = (const float*)d_in[2];
  const float* Wqkvu = (const float*)d_in[3];
  const float* Wout = (const float*)d_in[4];
  const float* bout = (const float*)d_in[5];
  const float* rmsw = (const float*)d_in[6];
  float* out = (float*)d_out;
  float* ws = (float*)d_ws;

  ushort_t* fused = (ushort_t*)(ws + FUSED_OFF);
  ushort_t* a2 = (ushort_t*)(ws + A2_OFF);
  ushort_t* hb = (ushort_t*)(ws + HB_OFF);
  ushort_t* wqt = (ushort_t*)(ws + WQT_OFF);
  ushort_t* wot = (ushort_t*)(ws + WOT_OFF);
  ushort_t* qrb = (ushort_t*)(ws + QR_OFF);
  ushort_t* krb = (ushort_t*)(ws + KR_OFF);
  ushort_t* vtb = (ushort_t*)(ws + VT_OFF);
  float* tab = ws + TAB_OFF;
  int* mflag = (int*)(ws + FLAG_OFF);
  ushort_t* tsbp = (ushort_t*)(ws + TSB_OFF);
  unsigned char* mbits = (unsigned char*)(ws + MBITS_OFF);

  hstu_cvt_all<<<13825, 256, 0, stream>>>(hidden, hb, Wqkvu, wqt, Wout, wot, tab,
                                          (const unsigned int*)mask, mflag);
  hstu_gemm_silu_msk<<<1536 + 4096, 256, 0, stream>>>(
      hb, wqt, fused, (const int*)mask, (const unsigned char*)mask, mflag, bias, tsbp, mbits);
  hstu_prep2<<<6144, 256, 0, stream>>>(fused, (const float2*)tab, qrb, krb, vtb);
  hstu_attn<<<dim3(NH, Sq / 64, Bz), 512, 0, stream>>>(
      fused, qrb, krb, vtb, tsbp, (const unsigned int*)mbits, a2);
  hstu_gemm_out<<<dim3(Hh / 64, (Bz * Sq) / 128), 256, 0, stream>>>(a2, wot, bout, hidden, out);
  hstu_rms<<<Bz * Sq, 256, 0, stream>>>(out, rmsw);
}

// Round 16
// 306.459 us; speedup vs baseline: 1.2067x; 1.2067x over previous
//
#include <hip/hip_runtime.h>
#include <math.h>

// Problem constants (B=2, S=2048, H=1024, NH=8, HD=128)
static constexpr int Bz = 2;
static constexpr int Sq = 2048;
static constexpr int Hh = 1024;
static constexpr int NH = 8;
static constexpr int HD = 128;
static constexpr int H3 = 3072;
static constexpr int H6 = 6144;

typedef unsigned short ushort_t;
typedef float f32x4v __attribute__((ext_vector_type(4)));
typedef short s16x8 __attribute__((ext_vector_type(8)));

// Workspace layout in float units (×4 bytes). Peak 146.8 MB (< 152.04 known-good).
static constexpr size_t FUSED_OFF = 0;          // bf16 [4096][6144] = 12,582,912 f
static constexpr size_t A2_OFF    = 12582912;   // bf16 [4096][3072] =  6,291,456 f
static constexpr size_t HB_OFF    = 18874368;   // bf16 [4096][1024] (dead after gemm_silu)
static constexpr size_t WQT_OFF   = 20971520;   // bf16 [6144][1024] (dead after gemm_silu)
static constexpr size_t WOT_OFF   = 24117248;   // bf16 [1024][3072] =  1,572,864 f
static constexpr size_t QR_OFF    = 25690112;   // bf16 [4096][1024] =  2,097,152 f
static constexpr size_t KR_OFF    = 27787264;   // bf16 [4096][1024] =  2,097,152 f
static constexpr size_t VT_OFF    = 29884416;   // bf16 [16][128][2048] = 2,097,152 f
static constexpr size_t TAB_OFF   = 31981568;   // f32 S*64 float2 = 262,144 f
static constexpr size_t FLAG_OFF  = 32243712;   // 1 int (+pad)
static constexpr size_t TSB_OFF   = 32243716;   // bf16 [2][2048][2048] = 4,194,304 f
static constexpr size_t MBITS_OFF = 36438020;   // u32 [2][2048][64] = 262,144 f -> ends 36,700,164 f

__device__ __forceinline__ float silu_(float x) { return x / (1.0f + expf(-x)); }
__device__ __forceinline__ ushort_t f2bf(float x) {
  unsigned int u = __float_as_uint(x);
  u += 0x7fffu + ((u >> 16) & 1u);
  return (ushort_t)(u >> 16);
}
__device__ __forceinline__ float bf2f(ushort_t u) {
  return __uint_as_float(((unsigned int)u) << 16);
}
// async global->LDS 16B: per-lane global src, wave-uniform LDS base (+lane*16B by HW)
__device__ __forceinline__ void g2l16(const ushort_t* g, ushort_t* l) {
  __builtin_amdgcn_global_load_lds(
      (const __attribute__((address_space(1))) unsigned int*)g,
      (__attribute__((address_space(3))) unsigned int*)l, 16, 0, 0);
}

// ---------------- fused conversions + rope table + mask detect:
// blocks 0..4095: hidden f32->bf16 | 4096..10239: Wqkvu transpose | 10240..13311: Wout
// transpose | 13312..13823: rope table | 13824: mask dtype detect
__global__ __launch_bounds__(256) void hstu_cvt_all(const float* __restrict__ hidden,
                                                    ushort_t* __restrict__ hb,
                                                    const float* __restrict__ Wq,
                                                    ushort_t* __restrict__ wqt,
                                                    const float* __restrict__ Wo,
                                                    ushort_t* __restrict__ wot,
                                                    float* __restrict__ tab,
                                                    const unsigned int* __restrict__ m,
                                                    int* __restrict__ flag) {
  __shared__ float tbuf[32][33];
  const int blk = blockIdx.x;
  if (blk >= 13824) {  // detect: any 32-bit word > 1 => byte-packed bools
    __shared__ int s_any;
    if (threadIdx.x == 0) s_any = 0;
    __syncthreads();
    int any = 0;
    for (int i = threadIdx.x; i < 8192; i += 256)
      if (m[i] > 1u) any = 1;
    if (any) s_any = 1;
    __syncthreads();
    if (threadIdx.x == 0) *flag = s_any;
    return;
  }
  if (blk >= 13312) {  // rope table
    int t = (blk - 13312) * 256 + threadIdx.x;  // < S*64
    int i = t & 63;
    int s = t >> 6;
    float inv = powf(10000.0f, -(float)i / 64.0f);
    float sn, cs;
    sincosf((float)s * inv, &sn, &cs);
    tab[2 * t + 0] = cs;
    tab[2 * t + 1] = sn;
    return;
  }
  if (blk < 4096) {  // hidden copy-convert
    const int idx = blk * 256 + threadIdx.x;
    float4 v = *(const float4*)&hidden[(size_t)idx * 4];
    ushort4 o;
    o.x = f2bf(v.x); o.y = f2bf(v.y); o.z = f2bf(v.z); o.w = f2bf(v.w);
    *(ushort4*)&hb[(size_t)idx * 4] = o;
    return;
  }
  const float* in;
  ushort_t* out;
  int K, N, n0, k0;
  if (blk < 4096 + 6144) {
    const int j = blk - 4096;
    in = Wq; out = wqt; K = 1024; N = 6144;
    n0 = (j % 192) * 32; k0 = (j / 192) * 32;
  } else {
    const int j = blk - 10240;
    in = Wo; out = wot; K = 3072; N = 1024;
    n0 = (j % 32) * 32; k0 = (j / 32) * 32;
  }
  const int c = threadIdx.x & 31, rr = threadIdx.x >> 5;
#pragma unroll
  for (int p = 0; p < 4; ++p)
    tbuf[rr + p * 8][c] = in[(size_t)(k0 + rr + p * 8) * N + n0 + c];
  __syncthreads();
#pragma unroll
  for (int p = 0; p < 4; ++p)
    out[(size_t)(n0 + rr + p * 8) * K + k0 + c] = f2bf(tbuf[c][rr + p * 8]);
}

// ---------------- MEGA: GEMM1 (blocks 0..1535) || msk (blocks 1536..5631).
__global__ __launch_bounds__(256) void hstu_gemm_silu_msk(
    const ushort_t* __restrict__ A, const ushort_t* __restrict__ Bt,
    ushort_t* __restrict__ C, const int* __restrict__ mask32,
    const unsigned char* __restrict__ mask8, const int* __restrict__ mflag,
    const float* __restrict__ bias, ushort_t* __restrict__ tsb,
    unsigned char* __restrict__ mbits) {
  __shared__ ushort_t As[128 * 64];
  __shared__ ushort_t Bs[128 * 64];
  const int blk = blockIdx.x;
  const int tid = threadIdx.x;
  if (blk >= 1536) {  // ---- msk branch (no barriers, no LDS use)
    const size_t gt = (size_t)(blk - 1536) * 256 + tid;  // over B*S*S/8
    const size_t base = gt * 8;
    const int m_u8 = *mflag;
    int mk[8];
    if (m_u8) {
      uchar4 a = *(const uchar4*)&mask8[base];
      uchar4 b = *(const uchar4*)&mask8[base + 4];
      mk[0] = a.x; mk[1] = a.y; mk[2] = a.z; mk[3] = a.w;
      mk[4] = b.x; mk[5] = b.y; mk[6] = b.z; mk[7] = b.w;
    } else {
      int4 a = *(const int4*)&mask32[base];
      int4 b = *(const int4*)&mask32[base + 4];
      mk[0] = a.x; mk[1] = a.y; mk[2] = a.z; mk[3] = a.w;
      mk[4] = b.x; mk[5] = b.y; mk[6] = b.z; mk[7] = b.w;
    }
    float4 b0 = *(const float4*)&bias[base];
    float4 b1 = *(const float4*)&bias[base + 4];
    float bb[8] = {b0.x, b0.y, b0.z, b0.w, b1.x, b1.y, b1.z, b1.w};
    ushort_t ts[8];
    unsigned int byte = 0;
#pragma unroll
    for (int i = 0; i < 8; ++i) {
      ts[i] = f2bf(mk[i] ? bb[i] : 0.0f);
      byte |= (mk[i] ? 1u : 0u) << i;
    }
    *(s16x8*)&tsb[base] = *(s16x8*)ts;
    mbits[gt] = (unsigned char)byte;
    return;
  }
  // ---- GEMM branch: fused = silu(hidden_bf @ WqT^T)  M=4096 N=6144 K=1024
  constexpr int K = 1024, N = H6;
  const int lane = tid & 63, wid = tid >> 6;
  const int lo4 = lane & 15, hi2 = lane >> 4;
  const int wr = wid >> 1, wc = wid & 1;
  const int row0 = (blk / 48) * 128, col0 = (blk % 48) * 128;
  const int srow = lane >> 3, scol = (lane & 7) * 8;
  f32x4v acc[4][4];
#pragma unroll
  for (int i = 0; i < 4; ++i)
#pragma unroll
    for (int j = 0; j < 4; ++j) acc[i][j] = {0.f, 0.f, 0.f, 0.f};

  for (int k0 = 0; k0 < K; k0 += 64) {
    __syncthreads();
#pragma unroll
    for (int i = 0; i < 4; ++i) {
      const int rb = wid * 32 + i * 8;
      g2l16(&A[(size_t)(row0 + rb + srow) * K + k0 + scol], &As[rb * 64]);
      g2l16(&Bt[(size_t)(col0 + rb + srow) * K + k0 + scol], &Bs[rb * 64]);
    }
    __syncthreads();
#pragma unroll
    for (int kc = 0; kc < 2; ++kc) {
      s16x8 af[4], bfr[4];
#pragma unroll
      for (int mi = 0; mi < 4; ++mi)
        af[mi] = *(const s16x8*)&As[(wr * 64 + mi * 16 + lo4) * 64 + kc * 32 + hi2 * 8];
#pragma unroll
      for (int nj = 0; nj < 4; ++nj)
        bfr[nj] = *(const s16x8*)&Bs[(wc * 64 + nj * 16 + lo4) * 64 + kc * 32 + hi2 * 8];
#pragma unroll
      for (int mi = 0; mi < 4; ++mi)
#pragma unroll
        for (int nj = 0; nj < 4; ++nj)
          acc[mi][nj] = __builtin_amdgcn_mfma_f32_16x16x32_bf16(af[mi], bfr[nj], acc[mi][nj], 0, 0, 0);
    }
  }
#pragma unroll
  for (int mi = 0; mi < 4; ++mi)
#pragma unroll
    for (int nj = 0; nj < 4; ++nj)
#pragma unroll
      for (int r = 0; r < 4; ++r) {
        const int row = row0 + wr * 64 + mi * 16 + hi2 * 4 + r;
        const int col = col0 + wc * 64 + nj * 16 + lo4;
        C[(size_t)row * N + col] = f2bf(silu_(acc[mi][nj][r]));
      }
}

// ---------------- fused: rope precompute (2048 blk) + V transpose (4096 blk)
__global__ __launch_bounds__(256) void hstu_prep2(const ushort_t* __restrict__ fused,
                                                  const float2* __restrict__ tab,
                                                  ushort_t* __restrict__ qr,
                                                  ushort_t* __restrict__ kr,
                                                  ushort_t* __restrict__ vt) {
  __shared__ ushort_t tbuf[32][36];
  const int blk = blockIdx.x;
  if (blk < 2048) {  // rope
    const int idx = blk * 256 + threadIdx.x;
    const int row = idx >> 7;
    const int cg = (idx & 127) * 8;
    const int s = row & (Sq - 1);
    const float2* trow = &tab[(size_t)s * 64 + ((cg & 127) >> 1)];
    float2 t[4];
#pragma unroll
    for (int p = 0; p < 4; ++p) t[p] = trow[p];
    s16x8 q8 = *(const s16x8*)&fused[(size_t)row * H6 + 4 * Hh + cg];
    s16x8 k8 = *(const s16x8*)&fused[(size_t)row * H6 + 5 * Hh + cg];
    ushort_t qo[8], ko[8];
#pragma unroll
    for (int p = 0; p < 4; ++p) {
      float qx = bf2f((ushort_t)q8[2 * p]), qy = bf2f((ushort_t)q8[2 * p + 1]);
      float kx = bf2f((ushort_t)k8[2 * p]), ky = bf2f((ushort_t)k8[2 * p + 1]);
      qo[2 * p] = f2bf(qx * t[p].x - qy * t[p].y);
      qo[2 * p + 1] = f2bf(qy * t[p].x + qx * t[p].y);
      ko[2 * p] = f2bf(kx * t[p].x - ky * t[p].y);
      ko[2 * p + 1] = f2bf(ky * t[p].x + kx * t[p].y);
    }
    *(s16x8*)&qr[(size_t)row * Hh + cg] = *(s16x8*)qo;
    *(s16x8*)&kr[(size_t)row * Hh + cg] = *(s16x8*)ko;
    return;
  }
  // vt: vt[(b*8+h)*128+dd][m] = V[b][m][h*128+dd]
  const int j = blk - 2048;
  const int m0 = (j & 63) * 32, d0 = ((j >> 6) & 3) * 32, bh = j >> 8;
  const int b = bh >> 3, h = bh & 7;
  const int r = threadIdx.x >> 3, cg = (threadIdx.x & 7) * 4;
  *(ushort4*)&tbuf[r][cg] =
      *(const ushort4*)&fused[(size_t)(b * Sq + m0 + r) * H6 + 3 * Hh + h * HD + d0 + cg];
  __syncthreads();
  ushort4 o;
  o.x = tbuf[cg + 0][r]; o.y = tbuf[cg + 1][r]; o.z = tbuf[cg + 2][r]; o.w = tbuf[cg + 3][r];
  *(ushort4*)&vt[(size_t)(bh * HD + d0 + r) * Sq + m0 + cg] = o;
}

// ---------------- GEMM2: out = A2 @ WoT^T + b_out + hidden  M=4096 N=1024 K=3072, f32 out
__global__ __launch_bounds__(256) void hstu_gemm_out(const ushort_t* __restrict__ A,
                                                     const ushort_t* __restrict__ Bt,
                                                     const float* __restrict__ bout,
                                                     const float* __restrict__ hidden,
                                                     float* __restrict__ C) {
  constexpr int K = H3, N = Hh;
  __shared__ ushort_t As[128 * 64];
  __shared__ ushort_t Bs[64 * 64];
  const int tid = threadIdx.x, lane = tid & 63, wid = tid >> 6;
  const int lo4 = lane & 15, hi2 = lane >> 4;
  const int wr = wid >> 1, wc = wid & 1;
  const int row0 = blockIdx.y * 128, col0 = blockIdx.x * 64;
  const int srow = lane >> 3, scol = (lane & 7) * 8;
  f32x4v acc[4][2];
#pragma unroll
  for (int i = 0; i < 4; ++i)
#pragma unroll
    for (int j = 0; j < 2; ++j) acc[i][j] = {0.f, 0.f, 0.f, 0.f};

  for (int k0 = 0; k0 < K; k0 += 64) {
    __syncthreads();
#pragma unroll
    for (int i = 0; i < 4; ++i) {
      const int rb = wid * 32 + i * 8;
      g2l16(&A[(size_t)(row0 + rb + srow) * K + k0 + scol], &As[rb * 64]);
    }
#pragma unroll
    for (int i = 0; i < 2; ++i) {
      const int rb = wid * 16 + i * 8;
      g2l16(&Bt[(size_t)(col0 + rb + srow) * K + k0 + scol], &Bs[rb * 64]);
    }
    __syncthreads();
#pragma unroll
    for (int kc = 0; kc < 2; ++kc) {
      s16x8 af[4], bfr[2];
#pragma unroll
      for (int mi = 0; mi < 4; ++mi)
        af[mi] = *(const s16x8*)&As[(wr * 64 + mi * 16 + lo4) * 64 + kc * 32 + hi2 * 8];
#pragma unroll
      for (int nj = 0; nj < 2; ++nj)
        bfr[nj] = *(const s16x8*)&Bs[(wc * 32 + nj * 16 + lo4) * 64 + kc * 32 + hi2 * 8];
#pragma unroll
      for (int mi = 0; mi < 4; ++mi)
#pragma unroll
        for (int nj = 0; nj < 2; ++nj)
          acc[mi][nj] = __builtin_amdgcn_mfma_f32_16x16x32_bf16(af[mi], bfr[nj], acc[mi][nj], 0, 0, 0);
    }
  }
#pragma unroll
  for (int mi = 0; mi < 4; ++mi)
#pragma unroll
    for (int nj = 0; nj < 2; ++nj)
#pragma unroll
      for (int r = 0; r < 4; ++r) {
        const int row = row0 + wr * 64 + mi * 16 + hi2 * 4 + r;
        const int col = col0 + wc * 32 + nj * 16 + lo4;
        C[(size_t)row * N + col] = acc[mi][nj][r] + bout[col] + hidden[(size_t)row * N + col];
      }
}

// ---------------- fused attention (R13-measured optimum, 142 µs — exact revert).
// Block: (h, nblock, b), 8 waves, KVBLK=32, 3 barriers/iter, T14 split staging.
// Scores S^T via mfma(kf,qf); mask via Mt32 bit-plane; ts staged to Pl[2] by waves 0-3.
__global__ __launch_bounds__(512, 4) void hstu_attn(const ushort_t* __restrict__ fused,
                                                    const ushort_t* __restrict__ qr,
                                                    const ushort_t* __restrict__ kr,
                                                    const ushort_t* __restrict__ vt,
                                                    const ushort_t* __restrict__ tsb,
                                                    const unsigned int* __restrict__ mbits32,
                                                    ushort_t* __restrict__ a2) {
  __shared__ __align__(16) ushort_t Ks[32][136];
  __shared__ __align__(16) ushort_t KRs[32][136];
  __shared__ __align__(16) ushort_t Vt[128][40];   // Vt[dd][m]
  __shared__ __align__(16) ushort_t Pl[3][64][40]; // 0=plain 1=rope 2=ts
  __shared__ unsigned int Mt32[64];                // bit-packed mask row per n

  const int tid = threadIdx.x;
  const int lane = tid & 63;
  const int wid = tid >> 6;  // 0..7
  const int lo4 = lane & 15;
  const int hi2 = lane >> 4;
  const int h = blockIdx.x;        // x = head -> linear%8 = h -> XCD pinning
  const int n0 = blockIdx.y * 64;
  const int b = blockIdx.z;
  const float ivs = 1.0f / 2048.0f;
  constexpr int NT = Sq / 32;

  // staging index constants
  const int krow = tid >> 4, kcol = (tid & 15) * 8;       // K/KR: 32 x 128
  const int vdd = tid >> 2, vmg = (tid & 3) * 8;          // Vt: 128 x 32
  const int trow = (tid & 255) >> 2, tmg = (tid & 3) * 8; // ts: 64 x 32 (waves 0-3)
  const size_t kbase = (size_t)b * Sq * H6 + 5 * Hh + h * HD + kcol;
  const size_t krbase = (size_t)b * Sq * Hh + h * HD + kcol;
  const size_t vbase = (size_t)((b * NH + h) * HD + vdd) * Sq + vmg;
  const size_t tbase = (size_t)(b * Sq + n0 + trow) * Sq + tmg;
  const size_t mbase = (size_t)(b * Sq + n0 + lane) * 64;  // u32 stride 64/row

  // ---- hoist Q fragments: wave = (type t_w, row-quarter rq)
  const int t_w = wid >> 2;  // 0=plain 1=rope
  const int rq = wid & 3;
  s16x8 qf[4];
  {
    const int row = tid >> 4;
    const int colg = (tid & 15) * 8;
#pragma unroll
    for (int half = 0; half < 2; ++half) {
      const size_t gr = (size_t)(b * Sq + n0 + half * 32 + row);
      *(s16x8*)&Ks[row][colg] = *(const s16x8*)&fused[gr * H6 + 4 * Hh + h * HD + colg];
      *(s16x8*)&KRs[row][colg] = *(const s16x8*)&qr[gr * Hh + h * HD + colg];
      __syncthreads();
      if ((rq >> 1) == half) {
        const int lrow = (rq & 1) * 16 + lo4;
        const ushort_t(*Qsrc)[136] = t_w ? KRs : Ks;
#pragma unroll
        for (int c = 0; c < 4; ++c)
          qf[c] = *(const s16x8*)&Qsrc[lrow][c * 32 + hi2 * 8];
      }
      __syncthreads();
    }
  }

  const f32x4v zero4 = {0.f, 0.f, 0.f, 0.f};
  f32x4v accO[3][2][2];
#pragma unroll
  for (int t = 0; t < 3; ++t)
#pragma unroll
    for (int rt = 0; rt < 2; ++rt)
#pragma unroll
      for (int ct = 0; ct < 2; ++ct) accO[t][rt][ct] = zero4;

  const int rh2 = wid >> 2;  // PV row-half
  const int cq = wid & 3;    // PV dd-quarter

  // prefetch registers
  s16x8 kreg, krreg, vreg, tsreg;
  unsigned int mreg;
#define LOADT(T)                                                            \
  {                                                                         \
    const size_t moff = (size_t)(T) * 32;                                   \
    kreg = *(const s16x8*)&fused[kbase + (moff + krow) * H6];               \
    krreg = *(const s16x8*)&kr[krbase + (moff + krow) * Hh];                \
    vreg = *(const s16x8*)&vt[vbase + moff];                                \
    if (wid < 4) tsreg = *(const s16x8*)&tsb[tbase + moff];                 \
    else if (wid == 4) mreg = mbits32[mbase + (T)];                         \
  }
#define WRITET()                                                            \
  {                                                                         \
    *(s16x8*)&Ks[krow][kcol] = kreg;                                        \
    *(s16x8*)&KRs[krow][kcol] = krreg;                                      \
    *(s16x8*)&Vt[vdd][vmg] = vreg;                                          \
    if (wid < 4) *(s16x8*)&Pl[2][trow][tmg] = tsreg;                        \
    else if (wid == 4) Mt32[lane] = mreg;                                   \
  }

  LOADT(0);
  WRITET();
  __syncthreads();

  for (int t = 0; t < NT; ++t) {
    if (t + 1 < NT) LOADT(t + 1);  // issue early (T14)
    // ---- scores: S^T via mfma(kf, qf); mask via bit-test on Mt32[n]
    {
      const ushort_t(*Kmat)[136] = t_w ? KRs : Ks;
      const int n = rq * 16 + lo4;
      const unsigned int bits = Mt32[n];
#pragma unroll
      for (int mt2 = 0; mt2 < 2; ++mt2) {
        f32x4v a = zero4;
#pragma unroll
        for (int c = 0; c < 4; ++c) {
          s16x8 kf = *(const s16x8*)&Kmat[mt2 * 16 + lo4][c * 32 + hi2 * 8];
          a = __builtin_amdgcn_mfma_f32_16x16x32_bf16(kf, qf[c], a, 0, 0, 0);
        }
        const int mb = mt2 * 16 + hi2 * 4;
        ushort4 po;
        po.x = ((bits >> (mb + 0)) & 1u) ? f2bf(fmaxf(a[0], 0.f) * ivs) : (ushort_t)0;
        po.y = ((bits >> (mb + 1)) & 1u) ? f2bf(fmaxf(a[1], 0.f) * ivs) : (ushort_t)0;
        po.z = ((bits >> (mb + 2)) & 1u) ? f2bf(fmaxf(a[2], 0.f) * ivs) : (ushort_t)0;
        po.w = ((bits >> (mb + 3)) & 1u) ? f2bf(fmaxf(a[3], 0.f) * ivs) : (ushort_t)0;
        *(ushort4*)&Pl[t_w][n][mb] = po;
      }
    }
    __syncthreads();
    // ---- PV: wave (rh2, cq): O[32 rows][32 dd] x 3 types
    {
      s16x8 af[3][2];
#pragma unroll
      for (int ty = 0; ty < 3; ++ty)
#pragma unroll
        for (int rt = 0; rt < 2; ++rt)
          af[ty][rt] = *(const s16x8*)&Pl[ty][rh2 * 32 + rt * 16 + lo4][hi2 * 8];
      s16x8 bfv[2];
#pragma unroll
      for (int ct = 0; ct < 2; ++ct)
        bfv[ct] = *(const s16x8*)&Vt[cq * 32 + ct * 16 + lo4][hi2 * 8];
#pragma unroll
      for (int ty = 0; ty < 3; ++ty)
#pragma unroll
        for (int rt = 0; rt < 2; ++rt)
#pragma unroll
          for (int ct = 0; ct < 2; ++ct)
            accO[ty][rt][ct] =
                __builtin_amdgcn_mfma_f32_16x16x32_bf16(af[ty][rt], bfv[ct], accO[ty][rt][ct], 0, 0, 0);
    }
    __syncthreads();
    // ---- write prefetched tile t+1 into LDS (write late, T14)
    if (t + 1 < NT) WRITET();
    __syncthreads();
  }
#undef LOADT
#undef WRITET

  // ---- epilogue: a2 = acc * gated (gated = fused[:, :3H], same 3H coordinate)
  const int toff[3] = {256, 0, 128};
#pragma unroll
  for (int ty = 0; ty < 3; ++ty)
#pragma unroll
    for (int rt = 0; rt < 2; ++rt)
#pragma unroll
      for (int ct = 0; ct < 2; ++ct)
#pragma unroll
        for (int r = 0; r < 4; ++r) {
          const int n = n0 + rh2 * 32 + rt * 16 + hi2 * 4 + r;
          const int dd = cq * 32 + ct * 16 + lo4;
          const int col3 = h * 384 + toff[ty] + dd;
          const float g = bf2f(fused[(size_t)(b * Sq + n) * H6 + col3]);
          a2[(size_t)(b * Sq + n) * H3 + col3] = f2bf(accO[ty][rt][ct][r] * g);
        }
}

// ---------------- RMS norm in-place (4096 rows x 1024), f32
__global__ __launch_bounds__(256) void hstu_rms(float* __restrict__ y,
                                                const float* __restrict__ w) {
  __shared__ float red[4];
  const int row = blockIdx.x;
  const int tid = threadIdx.x;
  float4 v = *(float4*)&y[(size_t)row * Hh + tid * 4];
  float ss = v.x * v.x + v.y * v.y + v.z * v.z + v.w * v.w;
#pragma unroll
  for (int o = 32; o > 0; o >>= 1) ss += __shfl_down(ss, o);
  if ((tid & 63) == 0) red[tid >> 6] = ss;
  __syncthreads();
  const float tot = red[0] + red[1] + red[2] + red[3];
  const float r = 1.0f / sqrtf(tot / (float)Hh + 1e-6f);
  float4 wv = *(const float4*)&w[tid * 4];
  v.x *= r * wv.x;
  v.y *= r * wv.y;
  v.z *= r * wv.z;
  v.w *= r * wv.w;
  *(float4*)&y[(size_t)row * Hh + tid * 4] = v;
}

extern "C" void kernel_launch(void* const* d_in, const int* in_sizes, int n_in,
                              void* d_out, int out_size, void* d_ws, size_t ws_size,
                              hipStream_t stream) {
  const float* hidden = (const float*)d_in[0];
  const void* mask = d_in[1];
  const float* bias = (const float*)d_in[2];
  const float* Wqkvu = (const float*)d_in[3];
  const float* Wout = (const float*)d_in[4];
  const float* bout = (const float*)d_in[5];
  const float* rmsw = (const float*)d_in[6];
  float* out = (float*)d_out;
  float* ws = (float*)d_ws;

  ushort_t* fused = (ushort_t*)(ws + FUSED_OFF);
  ushort_t* a2 = (ushort_t*)(ws + A2_OFF);
  ushort_t* hb = (ushort_t*)(ws + HB_OFF);
  ushort_t* wqt = (ushort_t*)(ws + WQT_OFF);
  ushort_t* wot = (ushort_t*)(ws + WOT_OFF);
  ushort_t* qrb = (ushort_t*)(ws + QR_OFF);
  ushort_t* krb = (ushort_t*)(ws + KR_OFF);
  ushort_t* vtb = (ushort_t*)(ws + VT_OFF);
  float* tab = ws + TAB_OFF;
  int* mflag = (int*)(ws + FLAG_OFF);
  ushort_t* tsbp = (ushort_t*)(ws + TSB_OFF);
  unsigned char* mbits = (unsigned char*)(ws + MBITS_OFF);

  hstu_cvt_all<<<13825, 256, 0, stream>>>(hidden, hb, Wqkvu, wqt, Wout, wot, tab,
                                          (const unsigned int*)mask, mflag);
  hstu_gemm_silu_msk<<<1536 + 4096, 256, 0, stream>>>(
      hb, wqt, fused, (const int*)mask, (const unsigned char*)mask, mflag, bias, tsbp, mbits);
  hstu_prep2<<<6144, 256, 0, stream>>>(fused, (const float2*)tab, qrb, krb, vtb);
  hstu_attn<<<dim3(NH, Sq / 64, Bz), 512, 0, stream>>>(
      fused, qrb, krb, vtb, tsbp, (const unsigned int*)mbits, a2);
  hstu_gemm_out<<<dim3(Hh / 64, (Bz * Sq) / 128), 256, 0, stream>>>(a2, wot, bout, hidden, out);
  hstu_rms<<<Bz * Sq, 256, 0, stream>>>(out, rmsw);
}